// Round 1
// 1984.694 us; speedup vs baseline: 1.2502x; 1.2502x over previous
//
#include <hip/hip_runtime.h>
#include <hip/hip_fp16.h>

typedef _Float16 f16;
typedef __attribute__((ext_vector_type(2))) _Float16 f16x2;
typedef __attribute__((ext_vector_type(2))) __fp16 h16x2;  // cvt_pkrtz native type
typedef __attribute__((ext_vector_type(8))) _Float16 f16x8;
typedef __attribute__((ext_vector_type(4))) float f32x4;

#define B_ 128
#define S_ 1024
#define I_ 768
#define H_ 256
#define O_ 6
#define G3 768  // 3*H

#if __has_builtin(__builtin_amdgcn_fdot2)
#define FDOT2(w, h, c) __builtin_amdgcn_fdot2((w), (h), (c), false)
#else
// fallback: should pattern-match to v_fma_mix_f32
#define FDOT2(w, h, c) ((c) + (float)(w)[0] * (float)(h)[0] + (float)(w)[1] * (float)(h)[1])
#endif

// ---------------------------------------------------------------------------
// prep: decay factors D[b,t], W_ih -> fp16, W_hh -> per-thread packed layout
// New Wp layout for (unit, k-half) recur partition:
//   thread tid = (i = tid&255, kh = tid>>9? no: tid>>8), wr[g*64+j] covers
//   W_hh[g*256+i][128*kh + 2j .. +2j+1]  =>  Wp[(g*64+j)*512 + tid]
// ---------------------------------------------------------------------------
__global__ __launch_bounds__(256) void prep_kernel(
    const float* __restrict__ rel, const float* __restrict__ alpha,
    const float* __restrict__ Wih, const float* __restrict__ Whh,
    float* __restrict__ D, f16* __restrict__ WihH, unsigned* __restrict__ Wp) {
  int i = blockIdx.x * 256 + threadIdx.x;
  const int nD = B_ * S_;       // 131072
  const int nW = G3 * I_;       // 589824
  const int nP = 192 * 512;     // 98304
  if (i < nD) {
    int t = i & (S_ - 1);
    float dt = t ? (rel[i] - rel[i - 1]) : rel[i];
    D[i] = __expf(-fabsf(alpha[0]) * dt);
  } else if (i < nD + nW) {
    int j = i - nD;
    WihH[j] = (f16)Wih[j];
  } else if (i < nD + nW + nP) {
    int k = i - nD - nW;
    int tid = k & 511;
    int kidx = k >> 9;           // 0..191
    int g = kidx >> 6, j = kidx & 63;
    int ii = tid & 255, kh = tid >> 8;
    int row = g * H_ + ii;
    int c = 128 * kh + 2 * j;
    union { unsigned u32; f16 h[2]; } pk;
    pk.h[0] = (f16)Whh[row * H_ + c];
    pk.h[1] = (f16)Whh[row * H_ + c + 1];
    Wp[k] = pk.u32;
  }
}

// ---------------------------------------------------------------------------
// gemm_xg: XG[m][n] = sum_k x[m][k] * W_ih[n][k] + b_ih[n], fp16 out
// 128x128x32 tiles, 4 waves (2x2), 16 MFMA 16x16x32_f16 per wave per K-iter
// ---------------------------------------------------------------------------
__global__ __launch_bounds__(256) void gemm_xg(
    const float* __restrict__ X, const f16* __restrict__ Wh,
    const float* __restrict__ bih, f16* __restrict__ XG) {
  __shared__ f16 As[128 * 40];  // padded stride 40 halves
  __shared__ f16 Bs[128 * 32];
  int bid = blockIdx.x;
  int nt = bid % 6, mt = bid / 6;  // nt fast -> A-tile L2 reuse
  int m0 = mt * 128, n0 = nt * 128;
  int tid = threadIdx.x, w = tid >> 6, lane = tid & 63;
  int wm = (w & 1) * 64, wn = (w >> 1) * 64;
  f32x4 acc[16];
#pragma unroll
  for (int i = 0; i < 16; i++) acc[i] = (f32x4){0.f, 0.f, 0.f, 0.f};
  int ar = tid >> 1, ah = tid & 1;  // A stage: row, 16-col half
  const float* aptr = X + (size_t)(m0 + ar) * I_ + ah * 16;
  int br = tid >> 1, bh = tid & 1;  // B stage: row, 16-col half

  for (int kk = 0; kk < 24; kk++) {
    int k0 = kk * 32;
    // ---- stage A (fp32 -> fp16 convert) ----
    const float4* af4 = (const float4*)(aptr + k0);
    float4 f0 = af4[0], f1 = af4[1], f2 = af4[2], f3 = af4[3];
    union { h16x2 h2[4]; uint4 v; } pa, pb;
    pa.h2[0] = __builtin_amdgcn_cvt_pkrtz(f0.x, f0.y);
    pa.h2[1] = __builtin_amdgcn_cvt_pkrtz(f0.z, f0.w);
    pa.h2[2] = __builtin_amdgcn_cvt_pkrtz(f1.x, f1.y);
    pa.h2[3] = __builtin_amdgcn_cvt_pkrtz(f1.z, f1.w);
    pb.h2[0] = __builtin_amdgcn_cvt_pkrtz(f2.x, f2.y);
    pb.h2[1] = __builtin_amdgcn_cvt_pkrtz(f2.z, f2.w);
    pb.h2[2] = __builtin_amdgcn_cvt_pkrtz(f3.x, f3.y);
    pb.h2[3] = __builtin_amdgcn_cvt_pkrtz(f3.z, f3.w);
    *(uint4*)&As[ar * 40 + ah * 16] = pa.v;
    *(uint4*)&As[ar * 40 + ah * 16 + 8] = pb.v;
    // ---- stage B (already fp16) ----
    const uint4* bg = (const uint4*)(Wh + (size_t)(n0 + br) * I_ + k0 + bh * 16);
    uint4 b0 = bg[0], b1 = bg[1];
    *(uint4*)&Bs[br * 32 + bh * 16] = b0;
    *(uint4*)&Bs[br * 32 + bh * 16 + 8] = b1;
    __syncthreads();
    // ---- fragments + MFMA ----
    int quad = lane >> 4, r16 = lane & 15;
    f16x8 afr[4], bfr[4];
#pragma unroll
    for (int m = 0; m < 4; m++)
      afr[m] = *(const f16x8*)&As[(wm + m * 16 + r16) * 40 + quad * 8];
#pragma unroll
    for (int n = 0; n < 4; n++)
      bfr[n] = *(const f16x8*)&Bs[(wn + n * 16 + r16) * 32 + quad * 8];
#pragma unroll
    for (int m = 0; m < 4; m++)
#pragma unroll
      for (int n = 0; n < 4; n++)
        acc[m * 4 + n] = __builtin_amdgcn_mfma_f32_16x16x32_f16(
            afr[m], bfr[n], acc[m * 4 + n], 0, 0, 0);
    __syncthreads();
  }
  // ---- epilogue: C/D layout col=lane&15, row=(lane>>4)*4+reg ----
  int col = lane & 15, rb = (lane >> 4) * 4;
#pragma unroll
  for (int n = 0; n < 4; n++) {
    int gn = n0 + wn + n * 16 + col;
    float bv = bih[gn];
#pragma unroll
    for (int m = 0; m < 4; m++) {
      f32x4 a = acc[m * 4 + n];
      int gm0 = m0 + wm + m * 16 + rb;
#pragma unroll
      for (int r = 0; r < 4; r++)
        XG[(size_t)(gm0 + r) * G3 + gn] = (f16)(a[r] + bv);
    }
  }
}

// ---------------------------------------------------------------------------
// recur: one wg per (batch, seq-half), 512 threads.
// Partition: thread = (unit i = tid&255, k-half kh = tid>>8). kh is
// wave-uniform, so the h-broadcast via readlane stays legal: hv holds the
// 64 half2 of this wave's k-half; 64 readlanes feed 192 fdot2 (3 gates).
// Exchange: kh=1 writes 3 consecutive floats (conflict-free), kh=0 adds and
// finishes all 3 gates for its unit (wave-uniform, no lane divergence).
// h double-buffered in LDS -> 2 barriers/step. Balanced segments:
// seg0 = [0,576), seg1 = [448,1024) storing t>=576 (same 128-step burn-in).
// ---------------------------------------------------------------------------
__global__ __launch_bounds__(512, 2) void recur_kernel(
    const f16* __restrict__ XG, const unsigned* __restrict__ Wp,
    const float* __restrict__ D, const float* __restrict__ bhh,
    f16* __restrict__ HS) {
  __shared__ unsigned h_pk[2][128];  // double-buffered h as half2
  __shared__ float part[3 * 256];    // kh=1 partials, [g][i] consecutive
  __shared__ float Ds[576];
  int bx = blockIdx.x;
  int b = bx >> 1, seg = bx & 1;
  const int t0 = seg ? 448 : 0;
  const int t1 = seg ? 1024 : 576;
  const int ts = seg ? 576 : 0;
  int tid = threadIdx.x, lane = tid & 63;
  int i = tid & 255, kh = tid >> 8;
  unsigned wr[192];
#pragma unroll
  for (int k = 0; k < 192; k++) wr[k] = Wp[k * 512 + tid];
  for (int t = tid; t < 576; t += 512) Ds[t] = D[b * S_ + t0 + t];
  if (tid < 128) h_pk[0][tid] = 0u;  // t0 is even for both segs -> buf 0
  float hreg = 0.f;
  float bh0 = 0.f, bh1 = 0.f, bh2 = 0.f;
  if (kh == 0) { bh0 = bhh[i]; bh1 = bhh[H_ + i]; bh2 = bhh[2 * H_ + i]; }
  const f16* xgb = XG + (size_t)b * S_ * G3 + i;
  float xr = 0.f, xz = 0.f, xn = 0.f;
  if (kh == 0) {  // prefetch xg for t0
    const f16* xp = xgb + (size_t)t0 * G3;
    xr = (float)xp[0]; xz = (float)xp[H_]; xn = (float)xp[2 * H_];
  }
  __syncthreads();

  for (int t = t0; t < t1; t++) {
    unsigned hv = h_pk[t & 1][(kh << 6) + lane];  // 2-way broadcast, free
    float a0 = 0.f, a1 = 0.f, a2 = 0.f, a3 = 0.f, a4 = 0.f, a5 = 0.f;
#pragma unroll
    for (int j = 0; j < 64; j += 2) {
      int s0 = __builtin_amdgcn_readlane((int)hv, j);
      int s1 = __builtin_amdgcn_readlane((int)hv, j + 1);
      union { int i32; f16x2 h; } c0, c1;
      c0.i32 = s0; c1.i32 = s1;
      union { unsigned u32; f16x2 h; } w0, w1, w2, w3, w4, w5;
      w0.u32 = wr[j];       w1.u32 = wr[64 + j];     w2.u32 = wr[128 + j];
      w3.u32 = wr[j + 1];   w4.u32 = wr[64 + j + 1]; w5.u32 = wr[128 + j + 1];
      a0 = FDOT2(w0.h, c0.h, a0);
      a1 = FDOT2(w1.h, c0.h, a1);
      a2 = FDOT2(w2.h, c0.h, a2);
      a3 = FDOT2(w3.h, c1.h, a3);
      a4 = FDOT2(w4.h, c1.h, a4);
      a5 = FDOT2(w5.h, c1.h, a5);
    }
    float pr = a0 + a3, pz = a1 + a4, pn = a2 + a5;
    if (kh) {  // wave-uniform branch; consecutive addresses, conflict-free
      part[i] = pr; part[256 + i] = pz; part[512 + i] = pn;
    }
    __syncthreads();
    if (!kh) {
      float Dt = Ds[t - t0];
      // decay commutes with the matvec: hg = (D*h) @ W^T = D * (h @ W^T)
      float hr = (pr + part[i]) * Dt + bh0;
      float hz = (pz + part[256 + i]) * Dt + bh1;
      float hn = (pn + part[512 + i]) * Dt + bh2;
      float r = 1.f / (1.f + __expf(-(xr + hr)));
      float z = 1.f / (1.f + __expf(-(xz + hz)));
      float pre = xn + r * hn;
      float e = __expf(-2.f * pre);
      float nn = (1.f - e) / (1.f + e);  // tanh
      hreg = (1.f - z) * nn + z * (hreg * Dt);
      f16 h16 = (f16)hreg;
      ((f16*)h_pk[(t + 1) & 1])[i] = h16;  // ds_write_b16, disjoint halves
      if (t >= ts) HS[(size_t)(b * S_ + t) * H_ + i] = h16;  // from register
      if (t + 1 < t1) {  // prefetch next xg; latency hides under next dot
        const f16* xp = xgb + (size_t)(t + 1) * G3;
        xr = (float)xp[0]; xz = (float)xp[H_]; xn = (float)xp[2 * H_];
      }
    }
    __syncthreads();
  }
}

// ---------------------------------------------------------------------------
// fc: out[r][o] = hs[r][:] . W_fc[o][:] + b_fc[o]; one wave per row
// ---------------------------------------------------------------------------
__global__ __launch_bounds__(256) void fc_kernel(
    const f16* __restrict__ HS, const float* __restrict__ Wfc,
    const float* __restrict__ bfc, float* __restrict__ OUT) {
  int tid = threadIdx.x, wv = tid >> 6, lane = tid & 63;
  int gw = blockIdx.x * 4 + wv;  // 2048 waves total
  float wreg[6][4];
#pragma unroll
  for (int o = 0; o < 6; o++)
#pragma unroll
    for (int c = 0; c < 4; c++) wreg[o][c] = Wfc[o * H_ + lane * 4 + c];
  for (int r = gw; r < B_ * S_; r += 2048) {
    union { uint2 v; f16 h[4]; } cv;
    cv.v = *(const uint2*)(HS + (size_t)r * H_ + lane * 4);
    float h0 = (float)cv.h[0], h1 = (float)cv.h[1];
    float h2 = (float)cv.h[2], h3 = (float)cv.h[3];
    float s[6];
#pragma unroll
    for (int o = 0; o < 6; o++)
      s[o] = h0 * wreg[o][0] + h1 * wreg[o][1] + h2 * wreg[o][2] + h3 * wreg[o][3];
#pragma unroll
    for (int m = 1; m < 64; m <<= 1)
#pragma unroll
      for (int o = 0; o < 6; o++) s[o] += __shfl_xor(s[o], m, 64);
    if (lane == 0)
#pragma unroll
      for (int o = 0; o < 6; o++) OUT[(size_t)r * O_ + o] = s[o] + bfc[o];
  }
}

// ---------------------------------------------------------------------------
extern "C" void kernel_launch(void* const* d_in, const int* in_sizes, int n_in,
                              void* d_out, int out_size, void* d_ws, size_t ws_size,
                              hipStream_t stream) {
  const float* x     = (const float*)d_in[0];
  const float* rel   = (const float*)d_in[1];
  const float* alpha = (const float*)d_in[2];
  const float* Wih   = (const float*)d_in[3];
  const float* bih   = (const float*)d_in[4];
  const float* Whh   = (const float*)d_in[5];
  const float* bhh   = (const float*)d_in[6];
  const float* Wfc   = (const float*)d_in[7];
  const float* bfc   = (const float*)d_in[8];
  float* out = (float*)d_out;
  char* ws = (char*)d_ws;
  // workspace layout (~258 MB total)
  f16* XG       = (f16*)(ws);                     // 201326592 B  [B*S,768] fp16
  f16* HS       = (f16*)(ws + 201326592);         //  67108864 B  [B*S,256] fp16
  float* D      = (float*)(ws + 268435456);       //    524288 B  [B,S]
  f16* WihH     = (f16*)(ws + 268959744);         //   1179648 B
  unsigned* Wp  = (unsigned*)(ws + 270139392);    //    393216 B
  prep_kernel<<<3200, 256, 0, stream>>>(rel, alpha, Wih, Whh, D, WihH, Wp);
  gemm_xg<<<6144, 256, 0, stream>>>(x, WihH, bih, XG);
  recur_kernel<<<256, 512, 0, stream>>>(XG, Wp, D, bhh, HS);
  fc_kernel<<<512, 256, 0, stream>>>(HS, Wfc, bfc, out);
}